// Round 1
// baseline (286.338 us; speedup 1.0000x reference)
//
#include <hip/hip_runtime.h>

typedef unsigned short u16;
typedef __attribute__((ext_vector_type(4)))  unsigned int u32x4;
typedef __attribute__((ext_vector_type(4)))  float        f32x4;
typedef __attribute__((ext_vector_type(4)))  u16          u16x4;
typedef __attribute__((ext_vector_type(8)))  __bf16       bf16x8;
typedef __attribute__((ext_vector_type(16))) float        f32x16;

#define NB 2
#define NH 8
#define NS 2048
#define ND 128

static __device__ __forceinline__ u16 f2b(float x) {
  return __builtin_bit_cast(u16, (__bf16)x);
}

// ---------------- pre-pass 1: f32 -> bf16 (q, k) ----------------
__global__ __launch_bounds__(256) void cvt_f32_bf16(const float* __restrict__ src,
                                                    u16* __restrict__ dst, int n4) {
  int i = blockIdx.x * 256 + threadIdx.x;
  if (i >= n4) return;
  f32x4 v = ((const f32x4*)src)[i];
  u16x4 o;
  o[0] = f2b(v[0]); o[1] = f2b(v[1]); o[2] = f2b(v[2]); o[3] = f2b(v[3]);
  ((u16x4*)dst)[i] = o;
}

// ---------------- pre-pass 2: V [bh][s][d] f32 -> Vt [bh][d][s] bf16 ----------------
__global__ __launch_bounds__(256) void vtrans(const float* __restrict__ v,
                                              u16* __restrict__ vt) {
  __shared__ u16 Lt[128][40];                       // pad 40: 80B rows, 16B aligned
  const int bh = blockIdx.y;
  const int s0 = blockIdx.x * 32;
  const int t  = threadIdx.x;
  const float* src = v + (size_t)(bh * NS + s0) * ND;
  const int srow = t >> 3;
#pragma unroll
  for (int it = 0; it < 4; ++it) {
    int c4 = (t & 7) + 8 * it;                      // float4 chunk 0..31
    f32x4 x = *(const f32x4*)(src + srow * ND + c4 * 4);
#pragma unroll
    for (int jj = 0; jj < 4; ++jj) Lt[c4 * 4 + jj][srow] = f2b(x[jj]);
  }
  __syncthreads();
  const int d = t >> 1, sh = t & 1;
  u32x4 a  = *(const u32x4*)&Lt[d][sh * 16];
  u32x4 bq = *(const u32x4*)&Lt[d][sh * 16 + 8];
  u16* dst = vt + (size_t)(bh * ND + d) * NS + s0 + sh * 16;
  *(u32x4*)dst       = a;
  *(u32x4*)(dst + 8) = bq;
}

// ---------------- async global->LDS 16B ----------------
static __device__ __forceinline__ void gll16(u16* l, const u16* g) {
  __builtin_amdgcn_global_load_lds((const __attribute__((address_space(1))) void*)g,
                                   (__attribute__((address_space(3))) void*)l, 16, 0, 0);
}

// ---------------- main fused kernel ----------------
// grid 256: h = bid&7 (XCD affinity), qt = bid>>3 (64 q-rows per block)
// 8 waves: b = w>>2, r = (w>>1)&1 (32-row q half), jp = w&1 (kv tile parity)
__global__ __launch_bounds__(512, 2) void retention_main(
    const u16* __restrict__ qb, const u16* __restrict__ kb, const u16* __restrict__ vt,
    const float* __restrict__ omask, float* __restrict__ out) {
  // [dbuf][jpar][batch][row][col] ; K rows 256B, Vt rows 64B (chunk-XOR swizzled via source)
  __shared__ u16 Kls[2][2][2][32][128];   // 64 KB
  __shared__ u16 Vls[2][2][2][128][32];   // 64 KB
  __shared__ u16 Pls[8][32][32];          // 16 KB (XOR-swizzled)

  const int tid  = threadIdx.x;
  const int w    = tid >> 6;
  const int lane = tid & 63;
  const int l31  = lane & 31;
  const int hh   = lane >> 5;

  const int h  = blockIdx.x & 7;
  const int qt = blockIdx.x >> 3;
  const int q0 = qt * 64;

  const int b  = w >> 2;
  const int r  = (w >> 1) & 1;
  const int jp = w & 1;

  // staging role decomposition (bijection over 8 waves)
  const int sjp  = w & 1;
  const int sb   = (w >> 1) & 1;
  const int half = (w >> 2) & 1;

  // Q fragments: 32 rows x 128 d, A-frag: row=l31, k=16*ka+8*hh+j
  bf16x8 qf[8];
  {
    const u16* qrow = qb + ((size_t)((b * NH + h) * NS) + q0 + r * 32 + l31) * ND;
#pragma unroll
    for (int ka = 0; ka < 8; ++ka)
      qf[ka] = __builtin_bit_cast(bf16x8, *(const u32x4*)(qrow + ka * 16 + hh * 8));
  }

  f32x16 acc[4];
#pragma unroll
  for (int n = 0; n < 4; ++n)
#pragma unroll
    for (int i = 0; i < 16; ++i) acc[n][i] = 0.0f;

  float mA[16], mB[16];

  auto STAGE = [&](int step, int db) {
    const int T = 2 * step + sjp;
    // K tile: 32 rows x 256B; LDS(j,c) <- global chunk c^(j&15)
    const u16* kg = kb + ((size_t)((sb * NH + h) * NS) + T * 32) * ND;
    u16* kl = &Kls[db][sjp][sb][0][0];
#pragma unroll
    for (int i = 0; i < 4; ++i) {
      int r0 = half * 16 + i * 4;
      int jr = r0 + (lane >> 4);
      int cc = (lane & 15) ^ (jr & 15);
      gll16(kl + r0 * 128, kg + jr * 128 + cc * 8);
    }
    // Vt tile: 128 rows x 64B; LDS(d,c) <- global chunk c^(d&3)
    const u16* vg = vt + (size_t)((sb * NH + h) * ND) * NS + T * 32;
    u16* vl = &Vls[db][sjp][sb][0][0];
#pragma unroll
    for (int i = 0; i < 4; ++i) {
      int r0 = half * 64 + i * 16;
      int rr = r0 + (lane >> 2);
      int cc = (lane & 3) ^ (rr & 3);
      gll16(vl + r0 * 32, vg + (size_t)rr * NS + cc * 8);
    }
  };

  auto LOADM = [&](float (&m)[16], int step) {
    const int T = 2 * step + jp;
    const float* mrow = omask + (size_t)h * NS * NS + (size_t)(q0 + r * 32) * NS + T * 32 + l31;
#pragma unroll
    for (int r16 = 0; r16 < 16; ++r16) {
      int qrow = (r16 & 3) + 8 * (r16 >> 2) + 4 * hh;   // D-frag row
      m[r16] = mrow[(size_t)qrow * NS];
    }
  };

  auto COMPUTE = [&](int db, float (&m)[16]) {
    const u16* Kt = &Kls[db][jp][b][0][0];
    const u16* Vw = &Vls[db][jp][b][0][0];
    f32x16 s;
#pragma unroll
    for (int i = 0; i < 16; ++i) s[i] = 0.0f;
    // QK^T: A=Q(32xd), B=K(j x d as [N][K]): lane col j=l31, chunk (2ka+hh)^(j&15)
#pragma unroll
    for (int ka = 0; ka < 8; ++ka) {
      int cc = (2 * ka + hh) ^ (l31 & 15);
      bf16x8 kf = __builtin_bit_cast(bf16x8, *(const u32x4*)(Kt + l31 * 128 + cc * 8));
      s = __builtin_amdgcn_mfma_f32_32x32x16_bf16(qf[ka], kf, s, 0, 0, 0);
    }
    // P = S * mask  -> bf16 -> swizzled LDS (row=qrow, elem j at pos j^(((qrow>>1)&3)<<3))
    u16* Pw = &Pls[w][0][0];
#pragma unroll
    for (int r16 = 0; r16 < 16; ++r16) {
      int qrow = (r16 & 3) + 8 * (r16 >> 2) + 4 * hh;
      int idx  = qrow * 32 + (l31 ^ ((((qrow) >> 1) & 3) << 3));
      Pw[idx] = f2b(s[r16] * m[r16]);
    }
    asm volatile("" ::: "memory");   // order P writes before A-frag reads (same wave)
    bf16x8 pa[2];
#pragma unroll
    for (int kk = 0; kk < 2; ++kk) {
      int idx = l31 * 32 + ((8 * hh + 16 * kk) ^ (((l31 >> 1) & 3) << 3));
      pa[kk] = __builtin_bit_cast(bf16x8, *(const u32x4*)(Pw + idx));
    }
    // PV: A=P(32q x 32j), B=Vt(d2 x j as [N][K]): col d2=32n+l31, chunk (2kk+hh)^(d2&3)
#pragma unroll
    for (int n = 0; n < 4; ++n) {
#pragma unroll
      for (int kk = 0; kk < 2; ++kk) {
        int cc = (2 * kk + hh) ^ (l31 & 3);
        bf16x8 vf = __builtin_bit_cast(bf16x8, *(const u32x4*)(Vw + (n * 32 + l31) * 32 + cc * 8));
        acc[n] = __builtin_amdgcn_mfma_f32_32x32x16_bf16(pa[kk], vf, acc[n], 0, 0, 0);
      }
    }
  };

  // ---- pipeline: 32 steps, each wave does tile T = 2*step + jp ----
  STAGE(0, 0);
  LOADM(mA, 0);
  __syncthreads();
  for (int it = 0; it < 16; ++it) {
    STAGE(2 * it + 1, 1);
    LOADM(mB, 2 * it + 1);
    COMPUTE(0, mA);
    __syncthreads();
    if (it < 15) { STAGE(2 * it + 2, 0); LOADM(mA, 2 * it + 2); }
    COMPUTE(1, mB);
    __syncthreads();
  }

  // ---- epilogue: combine jp partials, RMSNorm, store ----
  float* red = (float*)&Kls[0][0][0][0][0];   // 64 KB scratch, 4 x (32x128) f32
  const int wbr = b * 2 + r;
  if (jp == 1) {
#pragma unroll
    for (int n = 0; n < 4; ++n)
#pragma unroll
      for (int r16 = 0; r16 < 16; ++r16) {
        int qrow = (r16 & 3) + 8 * (r16 >> 2) + 4 * hh;
        red[(size_t)(wbr * 32 + qrow) * 128 + n * 32 + l31] = acc[n][r16];
      }
  }
  __syncthreads();
  if (jp == 0) {
#pragma unroll
    for (int n = 0; n < 4; ++n)
#pragma unroll
      for (int r16 = 0; r16 < 16; ++r16) {
        int qrow = (r16 & 3) + 8 * (r16 >> 2) + 4 * hh;
        acc[n][r16] += red[(size_t)(wbr * 32 + qrow) * 128 + n * 32 + l31];
      }
    float ss[16];
#pragma unroll
    for (int r16 = 0; r16 < 16; ++r16) {
      float t = 0.0f;
#pragma unroll
      for (int n = 0; n < 4; ++n) t += acc[n][r16] * acc[n][r16];
      ss[r16] = t;
    }
#pragma unroll
    for (int msk = 1; msk <= 16; msk <<= 1)
#pragma unroll
      for (int r16 = 0; r16 < 16; ++r16) ss[r16] += __shfl_xor(ss[r16], msk);
#pragma unroll
    for (int r16 = 0; r16 < 16; ++r16)
      ss[r16] = rsqrtf(ss[r16] * (1.0f / 128.0f) + 1e-6f);
    float* orow = out + ((size_t)((b * NH + h) * NS) + q0 + r * 32) * ND;
#pragma unroll
    for (int n = 0; n < 4; ++n)
#pragma unroll
      for (int r16 = 0; r16 < 16; ++r16) {
        int qrow = (r16 & 3) + 8 * (r16 >> 2) + 4 * hh;
        orow[(size_t)qrow * ND + n * 32 + l31] = acc[n][r16] * ss[r16];
      }
  }
}

extern "C" void kernel_launch(void* const* d_in, const int* in_sizes, int n_in,
                              void* d_out, int out_size, void* d_ws, size_t ws_size,
                              hipStream_t stream) {
  const float* q  = (const float*)d_in[0];
  const float* k  = (const float*)d_in[1];
  const float* v  = (const float*)d_in[2];
  const float* om = (const float*)d_in[3];
  float* out = (float*)d_out;

  const int NELT = NB * NH * NS * ND;       // 4,194,304
  u16* qb = (u16*)d_ws;
  u16* kb = qb + NELT;
  u16* vt = kb + NELT;

  const int n4 = NELT / 4;                  // 1,048,576
  cvt_f32_bf16<<<n4 / 256, 256, 0, stream>>>(q, qb, n4);
  cvt_f32_bf16<<<n4 / 256, 256, 0, stream>>>(k, kb, n4);
  vtrans<<<dim3(NS / 32, NB * NH), 256, 0, stream>>>(v, vt);
  retention_main<<<256, 512, 0, stream>>>(qb, kb, vt, om, out);
}